// Round 1
// 747.029 us; speedup vs baseline: 1.0384x; 1.0384x over previous
//
#include <hip/hip_runtime.h>
#include <stdint.h>

// MoE MLP: per expert e (8): gate_up = h_e(1024x2048) @ W1_e(2048x4096),
// act = up * relu(gate) (bf16, ws), out_e = act @ W2_e(2048x2048) -> fp32.
//
// R2: pre-convert inputs once per launch (HBM-bound pass): H -> bf16,
// W1/W2 -> bf16 TRANSPOSED [n][k]. Main GEMMs become the m97 structure:
// global_load_lds width-16 staging (no VALU repack, linear LDS, zero bank
// conflicts), double-buffered LDS, 1 barrier per K-step.
// Fallback to R1 kernels if ws_size < 256 MiB.

#define NEXP 8
#define DIM  2048
#define TOK  1024
#define NGU  4096
#define BM   128
#define BN   128
#define BK   32
#define LDST 40   // fallback-path LDS stride

typedef __attribute__((ext_vector_type(8))) short short8;
typedef __attribute__((ext_vector_type(4))) float f32x4;

// pack two fp32 -> two bf16 (round-half-up): 2 adds + 1 v_perm
__device__ __forceinline__ uint32_t pkbf(float lo, float hi) {
  return __builtin_amdgcn_perm(__float_as_uint(hi) + 0x8000u,
                               __float_as_uint(lo) + 0x8000u, 0x07060302u);
}

// scalar round-half-up (same rounding as pkbf)
__device__ __forceinline__ uint16_t bf16_rhu(float x) {
  return (uint16_t)((__float_as_uint(x) + 0x8000u) >> 16);
}

__device__ __forceinline__ uint16_t bf16_rne(float x) {
  uint32_t u = __float_as_uint(x);
  return (uint16_t)((u + 0x7fffu + ((u >> 16) & 1u)) >> 16);
}

// async global(16B/lane) -> LDS (wave-uniform base + lane*16)
__device__ __forceinline__ void gll16(const void* g, void* l) {
  typedef __attribute__((address_space(1))) uint32_t gas_t;
  typedef __attribute__((address_space(3))) uint32_t las_t;
  __builtin_amdgcn_global_load_lds((gas_t*)(uintptr_t)g,
                                   (las_t*)(uint32_t)(uintptr_t)l, 16, 0, 0);
}

// ---------------- conversion pre-pass ----------------

// fp32 -> bf16 elementwise (8 elems/thread/iter)
__global__ __launch_bounds__(256) void k_cvt(const float* __restrict__ s,
                                             uint16_t* __restrict__ d, int n8) {
  for (int i = blockIdx.x * 256 + threadIdx.x; i < n8; i += gridDim.x * 256) {
    const float4* p = (const float4*)(s + (size_t)i * 8);
    float4 x = p[0], y = p[1];
    *(uint4*)(d + (size_t)i * 8) =
        make_uint4(pkbf(x.x, x.y), pkbf(x.z, x.w), pkbf(y.x, y.y), pkbf(y.z, y.w));
  }
}

// fp32 [E][K][N] -> bf16 [E][N][K] (64x64 LDS-tiled transpose)
__global__ __launch_bounds__(256) void k_cvt_t(const float* __restrict__ src,
                                               uint16_t* __restrict__ dst,
                                               int K, int N) {
  __shared__ uint16_t T[64][68];
  const int e = blockIdx.z;
  const int k0 = blockIdx.y << 6;
  const int n0 = blockIdx.x << 6;
  const float* s = src + (size_t)e * K * N;
  uint16_t* d = dst + (size_t)e * N * K;
  const int rr = threadIdx.x >> 4;
  const int cc = (threadIdx.x & 15) << 2;
#pragma unroll
  for (int p = 0; p < 4; ++p) {
    int kk = (p << 4) + rr;
    float4 v = *(const float4*)(s + (size_t)(k0 + kk) * N + n0 + cc);
    T[cc + 0][kk] = bf16_rhu(v.x);
    T[cc + 1][kk] = bf16_rhu(v.y);
    T[cc + 2][kk] = bf16_rhu(v.z);
    T[cc + 3][kk] = bf16_rhu(v.w);
  }
  __syncthreads();
#pragma unroll
  for (int p = 0; p < 4; ++p) {
    int nn = (p << 4) + rr;
    *(ushort4*)(d + (size_t)(n0 + nn) * K + k0 + cc) =
        make_ushort4(T[nn][cc], T[nn][cc + 1], T[nn][cc + 2], T[nn][cc + 3]);
  }
}

// ---------------- fast-path GEMMs (bf16, B^T, global_load_lds) ----------------

// K1: act = up * relu(gate). A = Hb[e] (bf16 [m][k]); Bg/Bu = W1T rows
// n0..n0+127 and n0+2048.. (bf16 [n][k]).
__global__ __launch_bounds__(256, 2) void k_gateup_b(const uint16_t* __restrict__ Hb,
                                                     const uint16_t* __restrict__ W1T,
                                                     uint16_t* __restrict__ ACT) {
  __shared__ uint16_t As[2][BM * BK];
  __shared__ uint16_t Bg[2][BN * BK];
  __shared__ uint16_t Bu[2][BN * BK];

  const int tid = threadIdx.x;
  const int e   = blockIdx.z;
  const int m0  = blockIdx.y * BM;
  const int n0  = blockIdx.x * BN;

  // staging: thread -> (row tid>>2 [+64 round 1], k-part (tid&3)*8), 16B/load
  const int sr = tid >> 2;
  const int sk = (tid & 3) << 3;
  const uint16_t* aG = Hb  + (size_t)(e * TOK + m0 + sr) * DIM + sk;
  const uint16_t* gG = W1T + ((size_t)e * NGU + n0 + sr) * DIM + sk;
  const uint16_t* uG = gG + (size_t)DIM * DIM;   // up rows: n0+2048..
  const int l0 = tid * 8;                         // ushort offset, round 0
  const int l1 = 2048 + tid * 8;                  // round 1 (rows +64)
  const size_t r1 = (size_t)64 * DIM;

  const int lane = tid & 63;
  const int wid  = tid >> 6;
  const int wr = (wid >> 1) << 6;
  const int wc = (wid & 1) << 6;
  const int lm = lane & 15;
  const int qd = lane >> 4;

  f32x4 accg[4][4], accu[4][4];
  const f32x4 zero = {0.f, 0.f, 0.f, 0.f};
#pragma unroll
  for (int i = 0; i < 4; ++i)
#pragma unroll
    for (int j = 0; j < 4; ++j) { accg[i][j] = zero; accu[i][j] = zero; }

#define K1_STAGE(c, kk)                         \
  do {                                          \
    gll16(aG + (kk),      &As[c][l0]);          \
    gll16(aG + (kk) + r1, &As[c][l1]);          \
    gll16(gG + (kk),      &Bg[c][l0]);          \
    gll16(gG + (kk) + r1, &Bg[c][l1]);          \
    gll16(uG + (kk),      &Bu[c][l0]);          \
    gll16(uG + (kk) + r1, &Bu[c][l1]);          \
  } while (0)

#define K1_COMPUTE(c)                                                          \
  do {                                                                         \
    const uint16_t* af = &As[c][(wr + lm) * BK + (qd << 3)];                   \
    const uint16_t* gf = &Bg[c][(wc + lm) * BK + (qd << 3)];                   \
    const uint16_t* uf = &Bu[c][(wc + lm) * BK + (qd << 3)];                   \
    short8 a[4], bg[4], bu[4];                                                 \
    _Pragma("unroll")                                                          \
    for (int i = 0; i < 4; ++i) a[i] = *(const short8*)(af + i * 16 * BK);     \
    _Pragma("unroll")                                                          \
    for (int j = 0; j < 4; ++j) {                                              \
      bg[j] = *(const short8*)(gf + j * 16 * BK);                              \
      bu[j] = *(const short8*)(uf + j * 16 * BK);                              \
    }                                                                          \
    _Pragma("unroll")                                                          \
    for (int i = 0; i < 4; ++i)                                                \
      _Pragma("unroll")                                                        \
      for (int j = 0; j < 4; ++j) {                                            \
        accg[i][j] = __builtin_amdgcn_mfma_f32_16x16x32_bf16(a[i], bg[j],      \
                                                             accg[i][j], 0, 0, 0); \
        accu[i][j] = __builtin_amdgcn_mfma_f32_16x16x32_bf16(a[i], bu[j],      \
                                                             accu[i][j], 0, 0, 0); \
      }                                                                        \
  } while (0)

  K1_STAGE(0, 0);
  __syncthreads();   // vmcnt(0) drain: buf0 ready

#pragma unroll 1
  for (int k0 = 0; k0 < DIM; k0 += 2 * BK) {
    // phase 0: stage buf1 (tile k0+BK) under compute of buf0 (tile k0)
    if (k0 + BK < DIM) K1_STAGE(1, k0 + BK);
    K1_COMPUTE(0);
    __syncthreads();
    // phase 1: stage buf0 (tile k0+2BK) under compute of buf1
    if (k0 + 2 * BK < DIM) K1_STAGE(0, k0 + 2 * BK);
    K1_COMPUTE(1);
    __syncthreads();
  }
#undef K1_STAGE
#undef K1_COMPUTE

  // epilogue: act = up * relu(gate) -> bf16 (RNE)
  uint16_t* actE = ACT + (size_t)(e * TOK + m0) * DIM + n0;
#pragma unroll
  for (int i = 0; i < 4; ++i)
#pragma unroll
    for (int j = 0; j < 4; ++j)
#pragma unroll
      for (int t = 0; t < 4; ++t) {
        int row = wr + i * 16 + qd * 4 + t;
        int col = wc + j * 16 + lm;
        float gv = accg[i][j][t];
        float uv = accu[i][j][t];
        actE[(size_t)row * DIM + col] = bf16_rne(uv * fmaxf(gv, 0.f));
      }
}

// K2: out = act @ W2. A = ACT[e] (bf16 [m][k]); B = W2T rows n0.. (bf16 [n][k]).
__global__ __launch_bounds__(256, 2) void k_down_b(const uint16_t* __restrict__ ACT,
                                                   const uint16_t* __restrict__ W2T,
                                                   float* __restrict__ OUT) {
  __shared__ uint16_t As[2][BM * BK];
  __shared__ uint16_t Bs[2][BN * BK];

  const int tid = threadIdx.x;
  const int e   = blockIdx.z;
  const int m0  = blockIdx.y * BM;
  const int n0  = blockIdx.x * BN;

  const int sr = tid >> 2;
  const int sk = (tid & 3) << 3;
  const uint16_t* aG = ACT + (size_t)(e * TOK + m0 + sr) * DIM + sk;
  const uint16_t* bG = W2T + ((size_t)e * DIM + n0 + sr) * DIM + sk;
  const int l0 = tid * 8;
  const int l1 = 2048 + tid * 8;
  const size_t r1 = (size_t)64 * DIM;

  const int lane = tid & 63;
  const int wid  = tid >> 6;
  const int wr = (wid >> 1) << 6;
  const int wc = (wid & 1) << 6;
  const int lm = lane & 15;
  const int qd = lane >> 4;

  f32x4 acc[4][4];
  const f32x4 zero = {0.f, 0.f, 0.f, 0.f};
#pragma unroll
  for (int i = 0; i < 4; ++i)
#pragma unroll
    for (int j = 0; j < 4; ++j) acc[i][j] = zero;

#define K2_STAGE(c, kk)                         \
  do {                                          \
    gll16(aG + (kk),      &As[c][l0]);          \
    gll16(aG + (kk) + r1, &As[c][l1]);          \
    gll16(bG + (kk),      &Bs[c][l0]);          \
    gll16(bG + (kk) + r1, &Bs[c][l1]);          \
  } while (0)

#define K2_COMPUTE(c)                                                          \
  do {                                                                         \
    const uint16_t* af = &As[c][(wr + lm) * BK + (qd << 3)];                   \
    const uint16_t* bf = &Bs[c][(wc + lm) * BK + (qd << 3)];                   \
    short8 a[4], b[4];                                                         \
    _Pragma("unroll")                                                          \
    for (int i = 0; i < 4; ++i) a[i] = *(const short8*)(af + i * 16 * BK);     \
    _Pragma("unroll")                                                          \
    for (int j = 0; j < 4; ++j) b[j] = *(const short8*)(bf + j * 16 * BK);     \
    _Pragma("unroll")                                                          \
    for (int i = 0; i < 4; ++i)                                                \
      _Pragma("unroll")                                                        \
      for (int j = 0; j < 4; ++j)                                              \
        acc[i][j] = __builtin_amdgcn_mfma_f32_16x16x32_bf16(a[i], b[j],        \
                                                            acc[i][j], 0, 0, 0); \
  } while (0)

  K2_STAGE(0, 0);
  __syncthreads();

#pragma unroll 1
  for (int k0 = 0; k0 < DIM; k0 += 2 * BK) {
    if (k0 + BK < DIM) K2_STAGE(1, k0 + BK);
    K2_COMPUTE(0);
    __syncthreads();
    if (k0 + 2 * BK < DIM) K2_STAGE(0, k0 + 2 * BK);
    K2_COMPUTE(1);
    __syncthreads();
  }
#undef K2_STAGE
#undef K2_COMPUTE

  float* outE = OUT + (size_t)(e * TOK + m0) * DIM + n0;
#pragma unroll
  for (int i = 0; i < 4; ++i)
#pragma unroll
    for (int j = 0; j < 4; ++j)
#pragma unroll
      for (int t = 0; t < 4; ++t) {
        int row = wr + i * 16 + qd * 4 + t;
        int col = wc + j * 16 + lm;
        outE[(size_t)row * DIM + col] = acc[i][j][t];
      }
}

// ---------------- fallback path (R1 kernels, verbatim) ----------------

__global__ __launch_bounds__(256, 2) void k_gateup_fb(const float* __restrict__ H,
                                                      const float* __restrict__ W1,
                                                      uint16_t* __restrict__ ACT) {
  __shared__ uint16_t As[BM * LDST];
  __shared__ uint16_t Bg[BN * LDST];
  __shared__ uint16_t Bu[BN * LDST];

  const int tid = threadIdx.x;
  const int e   = blockIdx.z;
  const int m0  = blockIdx.y * BM;
  const int n0  = blockIdx.x * BN;

  const float* hA = H + (size_t)(e * TOK + m0) * DIM;
  const float* wE = W1 + (size_t)e * DIM * NGU;

  const int ar = tid >> 1;
  const int ak = (tid & 1) << 4;
  const float* aptr = hA + (size_t)ar * DIM + ak;
  uint16_t* asw = &As[ar * LDST + ak];

  const int bn = tid & 127;
  const int bk = (tid >> 7) << 4;
  const float* gptr = wE + (size_t)bk * NGU + (n0 + bn);
  const float* uptr = gptr + DIM;
  uint16_t* bgw = &Bg[bn * LDST + bk];
  uint16_t* buw = &Bu[bn * LDST + bk];

  const int lane = tid & 63;
  const int wid  = tid >> 6;
  const int wr = (wid >> 1) << 6;
  const int wc = (wid & 1) << 6;
  const int lm = lane & 15;
  const int qd = lane >> 4;

  f32x4 accg[4][4], accu[4][4];
  const f32x4 zero = {0.f, 0.f, 0.f, 0.f};
#pragma unroll
  for (int i = 0; i < 4; ++i)
#pragma unroll
    for (int j = 0; j < 4; ++j) { accg[i][j] = zero; accu[i][j] = zero; }

  const uint16_t* afr = &As[(wr + lm) * LDST + (qd << 3)];
  const uint16_t* gfr = &Bg[(wc + lm) * LDST + (qd << 3)];
  const uint16_t* ufr = &Bu[(wc + lm) * LDST + (qd << 3)];

  float4 a0 = *(const float4*)(aptr + 0);
  float4 a1 = *(const float4*)(aptr + 4);
  float4 a2 = *(const float4*)(aptr + 8);
  float4 a3 = *(const float4*)(aptr + 12);
  float g[16], u[16];
#pragma unroll
  for (int i = 0; i < 16; ++i) g[i] = gptr[(size_t)i * NGU];
#pragma unroll
  for (int i = 0; i < 16; ++i) u[i] = uptr[(size_t)i * NGU];

#pragma unroll 1
  for (int k0 = 0; k0 < DIM; k0 += BK) {
    uint4 aw0 = make_uint4(pkbf(a0.x, a0.y), pkbf(a0.z, a0.w),
                           pkbf(a1.x, a1.y), pkbf(a1.z, a1.w));
    uint4 aw1 = make_uint4(pkbf(a2.x, a2.y), pkbf(a2.z, a2.w),
                           pkbf(a3.x, a3.y), pkbf(a3.z, a3.w));
    uint4 gw0 = make_uint4(pkbf(g[0], g[1]),  pkbf(g[2], g[3]),
                           pkbf(g[4], g[5]),  pkbf(g[6], g[7]));
    uint4 gw1 = make_uint4(pkbf(g[8], g[9]),  pkbf(g[10], g[11]),
                           pkbf(g[12], g[13]), pkbf(g[14], g[15]));
    uint4 uw0 = make_uint4(pkbf(u[0], u[1]),  pkbf(u[2], u[3]),
                           pkbf(u[4], u[5]),  pkbf(u[6], u[7]));
    uint4 uw1 = make_uint4(pkbf(u[8], u[9]),  pkbf(u[10], u[11]),
                           pkbf(u[12], u[13]), pkbf(u[14], u[15]));

    __syncthreads();
    *(uint4*)(asw)     = aw0;
    *(uint4*)(asw + 8) = aw1;
    *(uint4*)(bgw)     = gw0;
    *(uint4*)(bgw + 8) = gw1;
    *(uint4*)(buw)     = uw0;
    *(uint4*)(buw + 8) = uw1;
    __syncthreads();

    aptr += BK;
    gptr += (size_t)BK * NGU;
    uptr += (size_t)BK * NGU;
    if (k0 + BK < DIM) {
      a0 = *(const float4*)(aptr + 0);
      a1 = *(const float4*)(aptr + 4);
      a2 = *(const float4*)(aptr + 8);
      a3 = *(const float4*)(aptr + 12);
#pragma unroll
      for (int i = 0; i < 16; ++i) g[i] = gptr[(size_t)i * NGU];
#pragma unroll
      for (int i = 0; i < 16; ++i) u[i] = uptr[(size_t)i * NGU];
    }

    short8 a[4], bgf[4], buf[4];
#pragma unroll
    for (int i = 0; i < 4; ++i) a[i] = *(const short8*)(afr + i * 16 * LDST);
#pragma unroll
    for (int j = 0; j < 4; ++j) {
      bgf[j] = *(const short8*)(gfr + j * 16 * LDST);
      buf[j] = *(const short8*)(ufr + j * 16 * LDST);
    }
#pragma unroll
    for (int i = 0; i < 4; ++i)
#pragma unroll
      for (int j = 0; j < 4; ++j) {
        accg[i][j] = __builtin_amdgcn_mfma_f32_16x16x32_bf16(a[i], bgf[j], accg[i][j], 0, 0, 0);
        accu[i][j] = __builtin_amdgcn_mfma_f32_16x16x32_bf16(a[i], buf[j], accu[i][j], 0, 0, 0);
      }
  }

  uint16_t* actE = ACT + (size_t)(e * TOK + m0) * DIM + n0;
#pragma unroll
  for (int i = 0; i < 4; ++i)
#pragma unroll
    for (int j = 0; j < 4; ++j)
#pragma unroll
      for (int t = 0; t < 4; ++t) {
        int row = wr + i * 16 + qd * 4 + t;
        int col = wc + j * 16 + lm;
        float gv = accg[i][j][t];
        float uv = accu[i][j][t];
        actE[(size_t)row * DIM + col] = bf16_rne(uv * fmaxf(gv, 0.f));
      }
}

__global__ __launch_bounds__(256, 2) void k_down_fb(const uint16_t* __restrict__ ACT,
                                                    const float* __restrict__ W2,
                                                    float* __restrict__ OUT) {
  __shared__ uint16_t Bs[BN * LDST];

  const int tid = threadIdx.x;
  const int e   = blockIdx.z;
  const int m0  = blockIdx.y * BM;
  const int n0  = blockIdx.x * BN;

  const uint16_t* aA = ACT + (size_t)(e * TOK + m0) * DIM;
  const float* wE = W2 + (size_t)e * DIM * DIM;

  const int bn = tid & 127;
  const int bk = (tid >> 7) << 4;
  const float* bptr = wE + (size_t)bk * DIM + (n0 + bn);
  uint16_t* bsw = &Bs[bn * LDST + bk];

  const int lane = tid & 63;
  const int wid  = tid >> 6;
  const int wr = (wid >> 1) << 6;
  const int wc = (wid & 1) << 6;
  const int lm = lane & 15;
  const int qd = lane >> 4;

  const uint16_t* agp = aA + (size_t)(wr + lm) * DIM + (qd << 3);

  f32x4 acc[4][4];
  const f32x4 zero = {0.f, 0.f, 0.f, 0.f};
#pragma unroll
  for (int i = 0; i < 4; ++i)
#pragma unroll
    for (int j = 0; j < 4; ++j) acc[i][j] = zero;

  const uint16_t* bfr = &Bs[(wc + lm) * LDST + (qd << 3)];

  short8 an[4];
#pragma unroll
  for (int i = 0; i < 4; ++i) an[i] = *(const short8*)(agp + (size_t)i * 16 * DIM);
  float b[16];
#pragma unroll
  for (int i = 0; i < 16; ++i) b[i] = bptr[(size_t)i * DIM];

#pragma unroll 1
  for (int k0 = 0; k0 < DIM; k0 += BK) {
    uint4 bw0 = make_uint4(pkbf(b[0], b[1]),  pkbf(b[2], b[3]),
                           pkbf(b[4], b[5]),  pkbf(b[6], b[7]));
    uint4 bw1 = make_uint4(pkbf(b[8], b[9]),  pkbf(b[10], b[11]),
                           pkbf(b[12], b[13]), pkbf(b[14], b[15]));
    short8 a[4];
#pragma unroll
    for (int i = 0; i < 4; ++i) a[i] = an[i];

    __syncthreads();
    *(uint4*)(bsw)     = bw0;
    *(uint4*)(bsw + 8) = bw1;
    __syncthreads();

    bptr += (size_t)BK * DIM;
    agp  += BK;
    if (k0 + BK < DIM) {
#pragma unroll
      for (int i = 0; i < 4; ++i) an[i] = *(const short8*)(agp + (size_t)i * 16 * DIM);
#pragma unroll
      for (int i = 0; i < 16; ++i) b[i] = bptr[(size_t)i * DIM];
    }

    short8 bf[4];
#pragma unroll
    for (int j = 0; j < 4; ++j) bf[j] = *(const short8*)(bfr + j * 16 * LDST);
#pragma unroll
    for (int i = 0; i < 4; ++i)
#pragma unroll
      for (int j = 0; j < 4; ++j)
        acc[i][j] = __builtin_amdgcn_mfma_f32_16x16x32_bf16(a[i], bf[j], acc[i][j], 0, 0, 0);
  }

  float* outE = OUT + (size_t)(e * TOK + m0) * DIM + n0;
#pragma unroll
  for (int i = 0; i < 4; ++i)
#pragma unroll
    for (int j = 0; j < 4; ++j)
#pragma unroll
      for (int t = 0; t < 4; ++t) {
        int row = wr + i * 16 + qd * 4 + t;
        int col = wc + j * 16 + lm;
        outE[(size_t)row * DIM + col] = acc[i][j][t];
      }
}

// ---------------- launch ----------------

extern "C" void kernel_launch(void* const* d_in, const int* in_sizes, int n_in,
                              void* d_out, int out_size, void* d_ws, size_t ws_size,
                              hipStream_t stream) {
  const float* H  = (const float*)d_in[0];   // (8192, 2048) fp32
  const float* W1 = (const float*)d_in[1];   // (8, 2048, 4096) fp32
  const float* W2 = (const float*)d_in[2];   // (8, 2048, 2048) fp32
  float* OUT = (float*)d_out;                // (8192, 2048) fp32

  const size_t ACT_B = (size_t)NEXP * TOK * DIM * 2;   // 33.5 MB
  const size_t HB_B  = (size_t)NEXP * TOK * DIM * 2;   // 33.5 MB
  const size_t W1T_B = (size_t)NEXP * DIM * NGU * 2;   // 134.2 MB
  const size_t W2T_B = (size_t)NEXP * DIM * DIM * 2;   // 67.1 MB

  dim3 blk(256);
  dim3 gg(DIM / BN, TOK / BM, NEXP);   // 16 x 8 x 8

  if (ws_size >= ACT_B + HB_B + W1T_B + W2T_B) {
    uint16_t* ACT = (uint16_t*)d_ws;
    uint16_t* Hb  = (uint16_t*)((char*)d_ws + ACT_B);
    uint16_t* W1T = (uint16_t*)((char*)d_ws + ACT_B + HB_B);
    uint16_t* W2T = (uint16_t*)((char*)d_ws + ACT_B + HB_B + W1T_B);

    k_cvt<<<2048, blk, 0, stream>>>(H, Hb, NEXP * TOK * DIM / 8);
    k_cvt_t<<<dim3(NGU / 64, DIM / 64, NEXP), blk, 0, stream>>>(W1, W1T, DIM, NGU);
    k_cvt_t<<<dim3(DIM / 64, DIM / 64, NEXP), blk, 0, stream>>>(W2, W2T, DIM, DIM);
    k_gateup_b<<<gg, blk, 0, stream>>>(Hb, W1T, ACT);
    k_down_b<<<gg, blk, 0, stream>>>(ACT, W2T, OUT);
  } else {
    uint16_t* ACT = (uint16_t*)d_ws;
    k_gateup_fb<<<gg, blk, 0, stream>>>(H, W1, ACT);
    k_down_fb<<<gg, blk, 0, stream>>>(ACT, W2, OUT);
  }
}